// Round 14
// baseline (107.647 us; speedup 1.0000x reference)
//
#include <hip/hip_runtime.h>

#define SEQ 512
#define BZ  64
#define DIN 1024
#define HID 256
#define DOUT 1024
#define NLANG 16

typedef __attribute__((ext_vector_type(8))) __bf16 bf16x8;
typedef __attribute__((ext_vector_type(4))) float f32x4;

__device__ __forceinline__ unsigned short f2bf(float f) {
    return __builtin_bit_cast(unsigned short, (__bf16)f);
}
__device__ __forceinline__ unsigned int f2bf_pack(float lo, float hi) {
    return (unsigned int)f2bf(lo) | ((unsigned int)f2bf(hi) << 16);
}
__device__ __forceinline__ void gload_lds16(const void* g, void* l) {
    __builtin_amdgcn_global_load_lds(
        (const __attribute__((address_space(1))) unsigned int*)g,
        (__attribute__((address_space(3))) unsigned int*)l, 16, 0, 0);
}

// W[lid][K][N] f32  ->  Wf[lid][N/16][K/32][64 lanes][8] bf16 (fragment-major).
// Fragment (n16,k32), lane l, elem j  =  W[lid][k32*32+(l>>4)*8+j][n16*16+(l&15)].
template<int K, int N>
__global__ __launch_bounds__(256)
void prep_frags(const float* __restrict__ src, unsigned short* __restrict__ dst) {
    constexpr int K32 = K / 32, N16 = N / 16;
    const int gid = blockIdx.x * 256 + threadIdx.x;
    const int l   = gid & 63;
    const int f   = gid >> 6;
    const int k32 = f & (K32 - 1);
    const int n16 = (f / K32) & (N16 - 1);
    const int lid = f / (K32 * N16);
    const float* s = src + ((long)lid * K + k32 * 32 + (l >> 4) * 8) * N + n16 * 16 + (l & 15);
    unsigned short o[8];
#pragma unroll
    for (int j = 0; j < 8; ++j) o[j] = f2bf(s[(long)j * N]);
    uint4 v;
    v.x = (unsigned int)o[0] | ((unsigned int)o[1] << 16);
    v.y = (unsigned int)o[2] | ((unsigned int)o[3] << 16);
    v.z = (unsigned int)o[4] | ((unsigned int)o[5] << 16);
    v.w = (unsigned int)o[6] | ((unsigned int)o[7] << 16);
    *(uint4*)(dst + (long)gid * 8) = v;
}

// ---------------- layer 1 ----------------
// h64x256 = relu(x @ W1 + b1). One block per (b, st), 8 waves.
// ONE change vs R12: x staged via global_load_lds DMA as f32 (no register
// round-trip -> no mid-loop vmcnt(0) drain; only the barrier drains, m97-style).
// LDS x image: f32 [64 r][16 chunk], chunk slot = c ^ (r&15), realized by
// pre-swizzled per-lane SOURCE addresses (LDS dest stays linear). Fragments
// read 2x ds_read_b128 f32 + cvt to bf16 at read time.
__global__ __launch_bounds__(512, 2)
void mlp_l1(const float* __restrict__ x,
            const unsigned short* __restrict__ W1f,
            const float* __restrict__ b1,
            const int* __restrict__ lang,
            unsigned short* __restrict__ h_ws) {
    __shared__ float sX[2][64 * 64];            // 2 x 16 KiB f32 x-tile (swizzled)
    __shared__ unsigned short sH[64 * 256];     // 32 KiB h-tile (bf16, swizzled)
    char* cH = (char*)sH;

    const int b  = blockIdx.x;
    const int st = blockIdx.y;
    const int t  = threadIdx.x;
    const int l  = t & 63;
    const int w  = t >> 6;                      // 0..7
    const int lid = lang[b];
    const long xstride = (long)BZ * DIN;
    const float* xb = x + (long)(st * 64) * xstride + (long)b * DIN;

    // per-lane DMA source (inverse-swizzled) for segments j=0,1:
    // LDS slot s_lin = (w*2+j)*64 + l  ->  r = seg*4 + (l>>4), chunk c = (l&15) ^ (r&15)
    const float* gsrc[2];
#pragma unroll
    for (int j = 0; j < 2; ++j) {
        int r = (w * 2 + j) * 4 + (l >> 4);
        int c = (l & 15) ^ (r & 15);
        gsrc[j] = xb + (long)r * xstride + c * 4;
    }
#define STAGE(KT, BUF)                                                            \
    {                                                                             \
        _Pragma("unroll")                                                         \
        for (int j = 0; j < 2; ++j)                                               \
            gload_lds16(gsrc[j] + (KT) * 64,                                      \
                        (char*)sX[BUF] + (w * 2 + j) * 1024);                     \
    }

    const f32x4 z4 = {0.f, 0.f, 0.f, 0.f};
    f32x4 acc1[4][2];
#pragma unroll
    for (int mi = 0; mi < 4; ++mi)
#pragma unroll
        for (int ni = 0; ni < 2; ++ni) acc1[mi][ni] = z4;

    const unsigned short* w1p = W1f + (((long)lid * 16 + w * 2) * 32) * 512 + (long)l * 8;
    // frag (ni, k32) at w1p + ni*16384 + k32*512   (shorts)

    float bvv[2];
#pragma unroll
    for (int ni = 0; ni < 2; ++ni)
        bvv[ni] = b1[lid * HID + w * 32 + ni * 16 + (l & 15)];

    STAGE(0, 0);
    bf16x8 bvp[2][2];
#pragma unroll
    for (int ni = 0; ni < 2; ++ni)
        bvp[0][ni] = __builtin_bit_cast(bf16x8, *(const uint4*)(w1p + (long)ni * 16384));
    __syncthreads();

    for (int kt = 0; kt < 16; ++kt) {
        if (kt < 15) STAGE(kt + 1, (kt + 1) & 1);
        const char* cX = (const char*)sX[kt & 1];
#pragma unroll
        for (int ks = 0; ks < 2; ++ks) {
            const int p = kt * 2 + ks;
            if (p < 31) {
#pragma unroll
                for (int ni = 0; ni < 2; ++ni)
                    bvp[(p + 1) & 1][ni] = __builtin_bit_cast(bf16x8,
                        *(const uint4*)(w1p + (long)ni * 16384 + (p + 1) * 512));
            }
            bf16x8 av[4];
#pragma unroll
            for (int mi = 0; mi < 4; ++mi) {
                const int r  = mi * 16 + (l & 15);
                const int c0 = ks * 8 + (l >> 4) * 2;
                const char* base = cX + r * 256;
                const float4 v0 = *(const float4*)(base + ((c0 ^ (r & 15)) << 4));
                const float4 v1 = *(const float4*)(base + (((c0 + 1) ^ (r & 15)) << 4));
                uint4 pk;
                pk.x = f2bf_pack(v0.x, v0.y);
                pk.y = f2bf_pack(v0.z, v0.w);
                pk.z = f2bf_pack(v1.x, v1.y);
                pk.w = f2bf_pack(v1.z, v1.w);
                av[mi] = __builtin_bit_cast(bf16x8, pk);
            }
#pragma unroll
            for (int mi = 0; mi < 4; ++mi)
#pragma unroll
                for (int ni = 0; ni < 2; ++ni)
                    acc1[mi][ni] = __builtin_amdgcn_mfma_f32_16x16x32_bf16(
                        av[mi], bvp[p & 1][ni], acc1[mi][ni], 0, 0, 0);
        }
        __syncthreads();
    }

    // epilogue: bias + relu + bf16 -> swizzled sH, then coalesced copy to h_ws
#pragma unroll
    for (int mi = 0; mi < 4; ++mi)
#pragma unroll
        for (int r = 0; r < 4; ++r) {
            int row = mi * 16 + (l >> 4) * 4 + r;
#pragma unroll
            for (int ni = 0; ni < 2; ++ni) {
                int col = w * 32 + ni * 16 + (l & 15);
                float v = acc1[mi][ni][r] + bvv[ni];
                v = v > 0.f ? v : 0.f;
                *(unsigned short*)(cH + row * 512 + (((col >> 3) ^ (row & 7)) << 4)
                                   + (col & 7) * 2) = f2bf(v);
            }
        }
    __syncthreads();

    uint4* hw = (uint4*)(h_ws + ((long)(b * 8 + st)) * 16384);
    const uint4* sq = (const uint4*)sH;
#pragma unroll
    for (int j = 0; j < 4; ++j)
        hw[t + 512 * j] = sq[t + 512 * j];
#undef STAGE
}

// ---------------- layer 2 ----------------
// y64x1024 = h @ W2 + b2. One block per (b, st), 8 waves. Byte-identical to
// the R11/R12 measured-good kernel (30us, ~5.3 TB/s effective).
__global__ __launch_bounds__(512, 2)
void mlp_l2(const unsigned short* __restrict__ h_ws,
            const unsigned short* __restrict__ W2f,
            const float* __restrict__ b2,
            const int* __restrict__ lang,
            float* __restrict__ y) {
    __shared__ unsigned short sH[64 * 256];     // 32 KiB h-tile (bf16, swizzled image)
    char* cH = (char*)sH;

    const int b  = blockIdx.x;
    const int st = blockIdx.y;
    const int t  = threadIdx.x;
    const int l  = t & 63;
    const int w  = t >> 6;                      // 0..7
    const int lid = lang[b];
    const int s0  = st * 64;

    const unsigned short* hw = h_ws + ((long)(b * 8 + st)) * 16384;
#pragma unroll
    for (int j = 0; j < 4; ++j) {
        int seg = w * 4 + j;                    // 1KB segments
        gload_lds16(hw + seg * 512 + l * 8, sH + seg * 512);
    }

    const unsigned short* w2p = W2f + (((long)lid * 64 + w * 8) * 8) * 512 + (long)l * 8;
    // frag (nc*4+ni, ks) at w2p + (nc*4+ni)*4096 + ks*512   (shorts)

    const f32x4 z4 = {0.f, 0.f, 0.f, 0.f};
    bf16x8 pv[2][4];
#pragma unroll
    for (int ni = 0; ni < 4; ++ni)
        pv[0][ni] = __builtin_bit_cast(bf16x8, *(const uint4*)(w2p + (long)ni * 4096));

    __syncthreads();   // drains vmcnt: h staging complete

    f32x4 acc[4][4];
    float b2v[4];
#pragma unroll
    for (int s = 0; s < 16; ++s) {
        const int nc = s >> 3, ks = s & 7, cur = s & 1;
        if (ks == 0) {
#pragma unroll
            for (int mi = 0; mi < 4; ++mi)
#pragma unroll
                for (int ni = 0; ni < 4; ++ni) acc[mi][ni] = z4;
#pragma unroll
            for (int ni = 0; ni < 4; ++ni)
                b2v[ni] = b2[lid * DOUT + w * 128 + nc * 64 + ni * 16 + (l & 15)];
        }
        if (s < 15) {
            const int ns = s + 1, nq = (ns >> 3) * 4, ks1 = ns & 7;
#pragma unroll
            for (int ni = 0; ni < 4; ++ni)
                pv[cur ^ 1][ni] = __builtin_bit_cast(bf16x8,
                    *(const uint4*)(w2p + (long)(nq + ni) * 4096 + ks1 * 512));
        }
        bf16x8 av2[4];
#pragma unroll
        for (int mi = 0; mi < 4; ++mi) {
            int row = mi * 16 + (l & 15);
            int ch  = ks * 4 + (l >> 4);
            av2[mi] = __builtin_bit_cast(bf16x8,
                *(const uint4*)(cH + row * 512 + ((ch ^ (row & 7)) << 4)));
        }
#pragma unroll
        for (int mi = 0; mi < 4; ++mi)
#pragma unroll
            for (int ni = 0; ni < 4; ++ni)
                acc[mi][ni] = __builtin_amdgcn_mfma_f32_16x16x32_bf16(
                    av2[mi], pv[cur][ni], acc[mi][ni], 0, 0, 0);
        if (ks == 7) {
#pragma unroll
            for (int mi = 0; mi < 4; ++mi)
#pragma unroll
                for (int r = 0; r < 4; ++r) {
                    int row = mi * 16 + (l >> 4) * 4 + r;
#pragma unroll
                    for (int ni = 0; ni < 4; ++ni) {
                        int col = w * 128 + nc * 64 + ni * 16 + (l & 15);
                        y[((long)(s0 + row) * BZ + b) * DOUT + col] =
                            acc[mi][ni][r] + b2v[ni];
                    }
                }
        }
    }
}

extern "C" void kernel_launch(void* const* d_in, const int* in_sizes, int n_in,
                              void* d_out, int out_size, void* d_ws, size_t ws_size,
                              hipStream_t stream) {
    const float* x    = (const float*)d_in[0];
    const int*   lang = (const int*)d_in[1];
    const float* W1   = (const float*)d_in[2];
    const float* b1   = (const float*)d_in[3];
    const float* W2   = (const float*)d_in[4];
    const float* b2   = (const float*)d_in[5];
    float* y = (float*)d_out;

    // ws: W1f bf16 (8 MiB) | W2f bf16 (8 MiB) | h image bf16 [64*8][16384] (16 MiB)
    unsigned short* W1f = (unsigned short*)d_ws;
    unsigned short* W2f = (unsigned short*)((char*)d_ws + (size_t)NLANG * HID * DIN * 2);
    unsigned short* hws = (unsigned short*)((char*)d_ws + (size_t)NLANG * HID * DIN * 2
                                                       + (size_t)NLANG * DOUT * HID * 2);

    prep_frags<DIN, HID><<<2048, 256, 0, stream>>>(W1, W1f);
    prep_frags<HID, DOUT><<<2048, 256, 0, stream>>>(W2, W2f);

    mlp_l1<<<dim3(BZ, SEQ / 64), 512, 0, stream>>>(x, W1f, b1, lang, hws);
    mlp_l2<<<dim3(BZ, SEQ / 64), 512, 0, stream>>>(hws, W2f, b2, lang, y);
}